// Round 13
// baseline (108.421 us; speedup 1.0000x reference)
//
#include <hip/hip_runtime.h>
#include <cstdint>

typedef __attribute__((ext_vector_type(8))) __bf16 bf16x8;
typedef __attribute__((ext_vector_type(4))) float f32x4;
typedef __attribute__((ext_vector_type(8))) short short8;
typedef __attribute__((ext_vector_type(4))) float float4v;
typedef __attribute__((ext_vector_type(4))) unsigned uint4v;
typedef __attribute__((ext_vector_type(4))) unsigned short ushort4v;

__device__ __forceinline__ unsigned short f2bf(float f) {
    unsigned u = __builtin_bit_cast(unsigned, f);
    u += 0x7fffu + ((u >> 16) & 1u);   // RNE
    return (unsigned short)(u >> 16);
}
__device__ __forceinline__ float bf2f(unsigned short s) {
    return __builtin_bit_cast(float, (unsigned)s << 16);
}
__device__ __forceinline__ f32x4 mfma_bf16(bf16x8 a, bf16x8 b, f32x4 c) {
    return __builtin_amdgcn_mfma_f32_16x16x32_bf16(a, b, c, 0, 0, 0);
}
// pack 2 f32 -> 2 bf16 in one u32 (lo = first arg)
__device__ __forceinline__ unsigned pkbf(float lo, float hi) {
    unsigned r;
    asm("v_cvt_pk_bf16_f32 %0, %1, %2" : "=v"(r) : "v"(lo), "v"(hi));
    return r;
}

#define GLD16(g, l)                                                                     \
    __builtin_amdgcn_global_load_lds((const __attribute__((address_space(1))) void*)(g), \
                                     (__attribute__((address_space(3))) void*)(l), 16, 0, 0)

// ---------------------------------------------------------------------------
// fp32 -> bf16 conversion, 8 elems/thread.
// ---------------------------------------------------------------------------
__global__ void __launch_bounds__(256) cvt_f32_bf16(const float* __restrict__ src,
                                                    unsigned short* __restrict__ dst, int n8) {
    const int stride = gridDim.x * blockDim.x;
    for (int i = blockIdx.x * blockDim.x + threadIdx.x; i < n8; i += stride) {
        const float4v* s = (const float4v*)(src + (size_t)i * 8);
        float4v v0 = s[0], v1 = s[1];
        short8 o;
        o[0] = (short)f2bf(v0[0]); o[1] = (short)f2bf(v0[1]);
        o[2] = (short)f2bf(v0[2]); o[3] = (short)f2bf(v0[3]);
        o[4] = (short)f2bf(v1[0]); o[5] = (short)f2bf(v1[1]);
        o[6] = (short)f2bf(v1[2]); o[7] = (short)f2bf(v1[3]);
        *(short8*)(dst + (size_t)i * 8) = o;
    }
}

// ---------------------------------------------------------------------------
// C[M,N] = A[M,K]*B[N,K]^T + bias[N].  128x128 tile, BK=32, 4 waves.
// Round-8 2-PHASE double-buffered LDS (known-good ~41us / 632 TF; at the
// 2-phase structure ceiling per catalog m230 — do not touch).
// MODE 0: f32 C (ldc=N).   MODE 1 (QKV): n0<2048 -> bf16 qk buffer (ldc=2048);
//   n0>=2048 -> V part written TRANSPOSED into vT[bh][d=64][token=2048] bf16.
// ---------------------------------------------------------------------------
template <int MODE>
__global__ void __launch_bounds__(256) gemm_bt(const unsigned short* __restrict__ A,
                                               const unsigned short* __restrict__ B,
                                               const float* __restrict__ bias,
                                               void* __restrict__ C,
                                               unsigned short* __restrict__ vT,
                                               int M, int N, int K) {
    __shared__ __attribute__((aligned(16))) unsigned short As[2][128 * 32];
    __shared__ __attribute__((aligned(16))) unsigned short Bs[2][128 * 32];
    const int tid = threadIdx.x;
    const int w = tid >> 6, lane = tid & 63;
    const int a = lane & 15, g = lane >> 4;
    const int m0 = blockIdx.y * 128, n0 = blockIdx.x * 128;
    const int wr = (w >> 1) * 64, wc = (w & 1) * 64;

    f32x4 acc[4][4];
#pragma unroll
    for (int i = 0; i < 4; i++)
#pragma unroll
        for (int j = 0; j < 4; j++) acc[i][j] = (f32x4)(0.0f);

    const int r0 = tid >> 2;
    const int c0 = (tid & 3) * 8;
    const unsigned short* gA0 = A + (size_t)(m0 + r0) * K + c0;
    const unsigned short* gA1 = A + (size_t)(m0 + 64 + r0) * K + c0;
    const unsigned short* gB0 = B + (size_t)(n0 + r0) * K + c0;
    const unsigned short* gB1 = B + (size_t)(n0 + 64 + r0) * K + c0;

#define GSTAGE(buf_, k0_)                                               \
    {                                                                   \
        char* la_ = (char*)&As[buf_][0] + w * 1024;                     \
        char* lb_ = (char*)&Bs[buf_][0] + w * 1024;                     \
        GLD16(gA0 + (k0_), la_);                                        \
        GLD16(gA1 + (k0_), la_ + 4096);                                 \
        GLD16(gB0 + (k0_), lb_);                                        \
        GLD16(gB1 + (k0_), lb_ + 4096);                                 \
    }

    GSTAGE(0, 0);
    __syncthreads();   // vmcnt(0) drain: tile 0 resident

    int cur = 0;
    for (int k0 = 0; k0 < K; k0 += 32) {
        if (k0 + 32 < K) GSTAGE(cur ^ 1, k0 + 32);  // in flight across compute

        bf16x8 af[4], bfr[4];
#pragma unroll
        for (int i = 0; i < 4; i++) {
            af[i]  = *(const bf16x8*)&As[cur][(wr + i * 16 + a) * 32 + g * 8];
            bfr[i] = *(const bf16x8*)&Bs[cur][(wc + i * 16 + a) * 32 + g * 8];
        }
#pragma unroll
        for (int i = 0; i < 4; i++)
#pragma unroll
            for (int j = 0; j < 4; j++) acc[i][j] = mfma_bf16(af[i], bfr[j], acc[i][j]);

        __syncthreads();   // readers done with buf cur; prefetched buf complete
        cur ^= 1;
    }
#undef GSTAGE

#pragma unroll
    for (int j = 0; j < 4; j++) {
        const int col = n0 + wc + j * 16 + a;
        const float bv = bias[col];
        if (MODE == 0) {
            float* Cf = (float*)C;
#pragma unroll
            for (int i = 0; i < 4; i++)
#pragma unroll
                for (int jr = 0; jr < 4; jr++) {
                    const int row = m0 + wr + i * 16 + g * 4 + jr;
                    Cf[(size_t)row * N + col] = acc[i][j][jr] + bv;
                }
        } else if (n0 < 2048) {  // Q/K part -> bf16, ldc = 2048
            unsigned short* Cb = (unsigned short*)C;
#pragma unroll
            for (int i = 0; i < 4; i++)
#pragma unroll
                for (int jr = 0; jr < 4; jr++) {
                    const int row = m0 + wr + i * 16 + g * 4 + jr;
                    Cb[(size_t)row * 2048 + col] = f2bf(acc[i][j][jr] + bv);
                }
        } else {  // V part -> vT[(b*16+h)][d][token], 4-token packs
            const int vd = col - 2048;
            const int hh = vd >> 6, dd = vd & 63;
#pragma unroll
            for (int i = 0; i < 4; i++) {
                const int token0 = m0 + wr + i * 16 + g * 4;
                const int bb = token0 >> 11, kl = token0 & 2047;
                ushort4v st;
#pragma unroll
                for (int jr = 0; jr < 4; jr++) st[jr] = f2bf(acc[i][j][jr] + bv);
                *(ushort4v*)(vT + ((size_t)((bb << 4) + hh) * 64 + dd) * 2048 + kl) = st;
            }
        }
    }
}

// ===========================================================================
// Causal flash attention v8: KVBLK=128 — halve iteration count, amortize the
// per-iteration fixed chain (1 barrier + 2 shuffles + rescale check) over 2x
// MFMA work.  Block = 512 thr / 8 waves = one 128-row q-block; k-tiles of 128
// (K[128][64] + V[64][128] = 32KB/tile, double-buffered = 64KB -> 2 blk/CU).
// Swapped QK^T + in-register softmax (exp2 domain), validated sigma layout
// generalized per-32-k-chunk: fragment f -> krow = 32(f>>1)+4(f&1)+srow.
// Balance: q-block i(s) = s<8 ? 15-s : s-8  (round-robin pairs sum 17 tiles).
// ===========================================================================

// stage k-tile t_ into buffer bf_: K 16KB + V 16KB, 4 GLD16/thread (512 thr).
// LDS dest LINEAR; source address carries the XOR swizzle (rule 21).
#define STAGE(bf_, t_)                                                  \
    {                                                                   \
        const size_t ko_ = (size_t)(t_) * 128 * LDQ;                    \
        const size_t vo_ = (size_t)(t_) * 128;                          \
        char* db_ = (char*)&KV[bf_][0] + w * 1024;                      \
        GLD16(sK0 + ko_, db_);                                          \
        GLD16(sK1 + ko_, db_ + 8192);                                   \
        GLD16(sV0 + vo_, db_ + 16384);                                  \
        GLD16(sV1 + vo_, db_ + 24576);                                  \
    }

__global__ void __launch_bounds__(512, 4) attn_fwd(const unsigned short* __restrict__ qk,
                                                   const unsigned short* __restrict__ vT,
                                                   unsigned short* __restrict__ o) {
    constexpr int SL = 2048, DH = 64, LDQ = 2048;
    constexpr float GAMMA = 0.18033688011112042f;  // 0.125 * log2(e)
    const int bh = blockIdx.x & 31;                // bh&7 -> XCD pinning
    const int s = blockIdx.x >> 5;                 // 0..15
    const int qb = (s < 8) ? 15 - s : s - 8;       // q-block; RR pairs sum 17 tiles
    const int b = bh >> 4, h = bh & 15;
    const int tid = threadIdx.x;
    const int w = tid >> 6, lane = tid & 63;       // w: 0..7
    const int n = lane & 15, g = lane >> 4;

    // per buffer: K[128][64] shorts 0..8191 | V[64][128] shorts 8192..16383
    __shared__ __attribute__((aligned(16))) unsigned short KV[2][16384];

    const int qs = qb * 128 + w * 16 + n;          // this lane's q row
    const int nt = qb + 1;                         // 128-wide k-tiles

    // ---- Q fragments (B-operand), prescaled into log2 domain ----
    bf16x8 qf[2];
    {
        const unsigned short* qp = qk + (size_t)(b * SL + qs) * LDQ + h * DH + g * 8;
        short8 la = *(const short8*)qp, lb = *(const short8*)(qp + 32);
        short8 s0, s1;
#pragma unroll
        for (int e = 0; e < 8; e++) {
            s0[e] = (short)f2bf(bf2f((unsigned short)la[e]) * GAMMA);
            s1[e] = (short)f2bf(bf2f((unsigned short)lb[e]) * GAMMA);
        }
        qf[0] = __builtin_bit_cast(bf16x8, s0);
        qf[1] = __builtin_bit_cast(bf16x8, s1);
    }

    // ---- staging sources (per-lane, pre-swizzled) ----
    // K: 512 thr cover rows 0..63 (round 0) / 64..127 (round 1); 8 units/row
    const int rK = tid >> 3;
    const int xrK = (rK & 3) | (((rK >> 3) & 1) << 2);   // same for rK and rK+64
    const int csK = (((tid & 7) ^ xrK) << 3);
    const unsigned short* sK0 = qk + (size_t)(b * SL + rK) * LDQ + 1024 + h * DH + csK;
    const unsigned short* sK1 = sK0 + (size_t)64 * LDQ;
    // V: rows d=0..31 / 32..63; 16 units/row; xr = d&7 (same for d, d+32)
    const int dV = tid >> 4;
    const int csV = (((tid & 15) ^ (dV & 7)) << 3);
    const unsigned short* sV0 = vT + (size_t)bh * DH * SL + (size_t)dV * SL + csV;
    const unsigned short* sV1 = sV0 + (size_t)32 * SL;

    // ---- fragment read offsets (swizzled) ----
    const int srow = 8 * (n >> 2) + (n & 3);
    const int xrq = (n & 3) | (((n >> 2) & 1) << 2);  // xr of all QKT rows
    const int offK0 = ((g ^ xrq) << 3);               // d 0..31 chunk
    const int offK1 = offK0 ^ 32;                     // d 32..63 chunk
    int offV[4];
#pragma unroll
    for (int kc = 0; kc < 4; kc++) offV[kc] = (((4 * kc + g) ^ (n & 7)) << 3);

    f32x4 of[4];
#pragma unroll
    for (int i = 0; i < 4; i++) of[i] = (f32x4)(0.0f);
    float m_i = -1e30f, l_i = 0.0f;

    STAGE(0, 0);
    __syncthreads();  // drains vmcnt before barrier

    for (int t = 0; t < nt; ++t) {
        const unsigned short* kvb = &KV[t & 1][0];
        if (t + 1 < nt) STAGE((t & 1) ^ 1, t + 1);  // loads fly during compute

        // ---- S^T: 8 fragments cover 128 k-rows ----
        f32x4 p[8];
#pragma unroll
        for (int f = 0; f < 8; f++) {
            const int r_ = srow + ((f >> 1) << 5) + ((f & 1) << 2);
            const bf16x8 ka_ = *(const bf16x8*)&kvb[r_ * 64 + offK0];
            const bf16x8 kc_ = *(const bf16x8*)&kvb[r_ * 64 + offK1];
            f32x4 acc_ = (f32x4)(0.0f);
            acc_ = mfma_bf16(ka_, qf[0], acc_);
            acc_ = mfma_bf16(kc_, qf[1], acc_);
            p[f] = acc_;
        }

        // ---- causal mask (diagonal tile only: block q-range == tile k-range) ----
        if (t == nt - 1) {
            const int k0 = t * 128;
#pragma unroll
            for (int f = 0; f < 8; f++) {
                const int kb_ = k0 + ((f >> 1) << 5) + ((f & 1) << 2) + 8 * g;
#pragma unroll
                for (int e = 0; e < 4; e++)
                    if (kb_ + e > qs) p[f][e] = -1e30f;
            }
        }

        // ---- in-register softmax (log2 domain), defer-max ----
        float mx = -1e30f;
#pragma unroll
        for (int f = 0; f < 8; f++) {
            const float a_ = fmaxf(fmaxf(p[f][0], p[f][1]), fmaxf(p[f][2], p[f][3]));
            mx = fmaxf(mx, a_);
        }
        mx = fmaxf(mx, __shfl_xor(mx, 16));
        mx = fmaxf(mx, __shfl_xor(mx, 32));
        if (!__all(mx <= m_i + 8.0f)) {
            const float mn_ = fmaxf(m_i, mx);
            const float al_ = __builtin_amdgcn_exp2f(m_i - mn_);
            l_i *= al_;
#pragma unroll
            for (int d_ = 0; d_ < 4; d_++) of[d_] = of[d_] * al_;
            m_i = mn_;
        }
        float rs = 0.0f;
#pragma unroll
        for (int f = 0; f < 8; f++)
#pragma unroll
            for (int e = 0; e < 4; e++) {
                p[f][e] = __builtin_amdgcn_exp2f(p[f][e] - m_i);
                rs += p[f][e];
            }
        l_i += rs;

        // ---- pack to PV B-fragments (sigma: pure in-lane) ----
        bf16x8 pf[4];
#pragma unroll
        for (int kc = 0; kc < 4; kc++) {
            uint4v u_;
            u_[0] = pkbf(p[2 * kc][0], p[2 * kc][1]);
            u_[1] = pkbf(p[2 * kc][2], p[2 * kc][3]);
            u_[2] = pkbf(p[2 * kc + 1][0], p[2 * kc + 1][1]);
            u_[3] = pkbf(p[2 * kc + 1][2], p[2 * kc + 1][3]);
            pf[kc] = __builtin_bit_cast(bf16x8, u_);
        }

        // ---- O^T += V^T P^T ----
        const unsigned short* vb = kvb + 8192;
#pragma unroll
        for (int df = 0; df < 4; df++) {
            const int vrow = (df * 16 + n) * 128;
#pragma unroll
            for (int kc = 0; kc < 4; kc++) {
                const bf16x8 va_ = *(const bf16x8*)&vb[vrow + offV[kc]];
                of[df] = mfma_bf16(va_, pf[kc], of[df]);
            }
        }

        __syncthreads();  // readers done with buf t&1; staged buf complete
    }

    // ---- epilogue: lane holds O[d = df*16+4g+r][q = qs] ----
    float rl = l_i;
    rl += __shfl_xor(rl, 16);
    rl += __shfl_xor(rl, 32);
    const float inv = 1.0f / rl;
    unsigned short* op = o + (size_t)(b * SL + qs) * 1024 + h * DH + 4 * g;
#pragma unroll
    for (int df = 0; df < 4; df++) {
        ushort4v st;
#pragma unroll
        for (int r = 0; r < 4; r++) st[r] = f2bf(of[df][r] * inv);
        *(ushort4v*)(op + df * 16) = st;
    }
}

// ---------------------------------------------------------------------------
extern "C" void kernel_launch(void* const* d_in, const int* in_sizes, int n_in,
                              void* d_out, int out_size, void* d_ws, size_t ws_size,
                              hipStream_t stream) {
    (void)in_sizes; (void)n_in; (void)out_size; (void)ws_size;
    const float* x    = (const float*)d_in[0];
    const float* Wqkv = (const float*)d_in[1];
    const float* bqkv = (const float*)d_in[2];
    const float* Wout = (const float*)d_in[3];
    const float* bout = (const float*)d_in[4];
    float* out = (float*)d_out;

    const int BS = 2, SL = 2048, DM = 1024;
    const int M = BS * SL;   // 4096
    const int N1 = 3 * DM;   // 3072
    const int K = DM;        // 1024

    // ws layout: x_bf 8M | wqkv_bf 6M | wout_bf 2M | qk 16M | vT 8M | attn_o 8M = 48M
    char* ws = (char*)d_ws;
    unsigned short* x_bf    = (unsigned short*)(ws);
    unsigned short* wqkv_bf = (unsigned short*)(ws + (8u << 20));
    unsigned short* wout_bf = (unsigned short*)(ws + (14u << 20));
    unsigned short* qkbuf   = (unsigned short*)(ws + (16u << 20));
    unsigned short* vTbuf   = (unsigned short*)(ws + (32u << 20));
    unsigned short* attn_o  = (unsigned short*)(ws + (40u << 20));

    cvt_f32_bf16<<<2048, 256, 0, stream>>>(x, x_bf, M * K / 8);
    cvt_f32_bf16<<<1536, 256, 0, stream>>>(Wqkv, wqkv_bf, N1 * K / 8);
    cvt_f32_bf16<<<512, 256, 0, stream>>>(Wout, wout_bf, DM * DM / 8);

    gemm_bt<1><<<dim3(N1 / 128, M / 128), 256, 0, stream>>>(x_bf, wqkv_bf, bqkv, qkbuf, vTbuf, M, N1, K);

    attn_fwd<<<dim3(512), 512, 0, stream>>>(qkbuf, vTbuf, attn_o);

    gemm_bt<0><<<dim3(DM / 128, M / 128), 256, 0, stream>>>(attn_o, wout_bf, bout, out, nullptr, M, DM, K);
}

// Round 14
// 105.148 us; speedup vs baseline: 1.0311x; 1.0311x over previous
//
#include <hip/hip_runtime.h>
#include <cstdint>

typedef __attribute__((ext_vector_type(8))) __bf16 bf16x8;
typedef __attribute__((ext_vector_type(4))) float f32x4;
typedef __attribute__((ext_vector_type(8))) short short8;
typedef __attribute__((ext_vector_type(4))) float float4v;
typedef __attribute__((ext_vector_type(4))) unsigned uint4v;
typedef __attribute__((ext_vector_type(4))) unsigned short ushort4v;

__device__ __forceinline__ unsigned short f2bf(float f) {
    unsigned u = __builtin_bit_cast(unsigned, f);
    u += 0x7fffu + ((u >> 16) & 1u);   // RNE
    return (unsigned short)(u >> 16);
}
__device__ __forceinline__ float bf2f(unsigned short s) {
    return __builtin_bit_cast(float, (unsigned)s << 16);
}
__device__ __forceinline__ f32x4 mfma_bf16(bf16x8 a, bf16x8 b, f32x4 c) {
    return __builtin_amdgcn_mfma_f32_16x16x32_bf16(a, b, c, 0, 0, 0);
}
// pack 2 f32 -> 2 bf16 in one u32 (lo = first arg), RNE
__device__ __forceinline__ unsigned pkbf(float lo, float hi) {
    unsigned r;
    asm("v_cvt_pk_bf16_f32 %0, %1, %2" : "=v"(r) : "v"(lo), "v"(hi));
    return r;
}

#define GLD16(g, l)                                                                     \
    __builtin_amdgcn_global_load_lds((const __attribute__((address_space(1))) void*)(g), \
                                     (__attribute__((address_space(3))) void*)(l), 16, 0, 0)

// ---------------------------------------------------------------------------
// fp32 -> bf16 for ALL THREE arrays in one launch (x | Wqkv | Wout).
// 1,048,576 octets total; 2048x256 threads x 2 octets each.
// ---------------------------------------------------------------------------
__global__ void __launch_bounds__(256) cvt_all(const float* __restrict__ x,
                                               const float* __restrict__ wqkv,
                                               const float* __restrict__ wout,
                                               unsigned short* __restrict__ xb,
                                               unsigned short* __restrict__ wqb,
                                               unsigned short* __restrict__ wob) {
    int i = blockIdx.x * blockDim.x + threadIdx.x;
#pragma unroll
    for (int k = 0; k < 2; k++, i += 524288) {
        const float* s;
        unsigned short* d;
        int off;
        if (i < 524288)      { s = x;    d = xb;  off = i; }
        else if (i < 917504) { s = wqkv; d = wqb; off = i - 524288; }
        else                 { s = wout; d = wob; off = i - 917504; }
        const float4v* sp = (const float4v*)(s + (size_t)off * 8);
        float4v v0 = sp[0], v1 = sp[1];
        uint4v u;
        u[0] = pkbf(v0[0], v0[1]);
        u[1] = pkbf(v0[2], v0[3]);
        u[2] = pkbf(v1[0], v1[1]);
        u[3] = pkbf(v1[2], v1[3]);
        *(uint4v*)(d + (size_t)off * 8) = u;
    }
}

// ---------------------------------------------------------------------------
// C[M,N] = A[M,K]*B[N,K]^T + bias[N].  128x128 tile, BK=32, 4 waves.
// 2-PHASE double-buffered LDS (known-good structure ceiling).
// NEW (T1): 1-D grid + bijective XCD swizzle; consecutive blocks on one XCD
// share the same B column-panel (n0) -> 256KB panel L2-resident, 32x reuse.
// MODE 0: f32 C (ldc=N).   MODE 1 (QKV): n0<2048 -> bf16 qk buffer (ldc=2048);
//   n0>=2048 -> V part written TRANSPOSED into vT[bh][d=64][token=2048] bf16.
// ---------------------------------------------------------------------------
template <int MODE>
__global__ void __launch_bounds__(256) gemm_bt(const unsigned short* __restrict__ A,
                                               const unsigned short* __restrict__ B,
                                               const float* __restrict__ bias,
                                               void* __restrict__ C,
                                               unsigned short* __restrict__ vT,
                                               int M, int N, int K) {
    __shared__ __attribute__((aligned(16))) unsigned short As[2][128 * 32];
    __shared__ __attribute__((aligned(16))) unsigned short Bs[2][128 * 32];
    const int tid = threadIdx.x;
    const int w = tid >> 6, lane = tid & 63;
    const int a = lane & 15, g = lane >> 4;

    // XCD swizzle: nwg % 8 == 0 (768 / 256) -> bijective.  by fastest within
    // a chunk -> same bx (B-panel) for 32 consecutive blocks on one XCD.
    const int cpx = gridDim.x >> 3;
    const int nf = ((int)blockIdx.x & 7) * cpx + ((int)blockIdx.x >> 3);
    const int bx = nf >> 5;          // N-tile (M/128 == 32)
    const int by = nf & 31;          // M-tile
    const int m0 = by * 128, n0 = bx * 128;
    const int wr = (w >> 1) * 64, wc = (w & 1) * 64;

    f32x4 acc[4][4];
#pragma unroll
    for (int i = 0; i < 4; i++)
#pragma unroll
        for (int j = 0; j < 4; j++) acc[i][j] = (f32x4)(0.0f);

    const int r0 = tid >> 2;
    const int c0 = (tid & 3) * 8;
    const unsigned short* gA0 = A + (size_t)(m0 + r0) * K + c0;
    const unsigned short* gA1 = A + (size_t)(m0 + 64 + r0) * K + c0;
    const unsigned short* gB0 = B + (size_t)(n0 + r0) * K + c0;
    const unsigned short* gB1 = B + (size_t)(n0 + 64 + r0) * K + c0;

#define GSTAGE(buf_, k0_)                                               \
    {                                                                   \
        char* la_ = (char*)&As[buf_][0] + w * 1024;                     \
        char* lb_ = (char*)&Bs[buf_][0] + w * 1024;                     \
        GLD16(gA0 + (k0_), la_);                                        \
        GLD16(gA1 + (k0_), la_ + 4096);                                 \
        GLD16(gB0 + (k0_), lb_);                                        \
        GLD16(gB1 + (k0_), lb_ + 4096);                                 \
    }

    GSTAGE(0, 0);
    __syncthreads();   // vmcnt(0) drain: tile 0 resident

    int cur = 0;
    for (int k0 = 0; k0 < K; k0 += 32) {
        if (k0 + 32 < K) GSTAGE(cur ^ 1, k0 + 32);  // in flight across compute

        bf16x8 af[4], bfr[4];
#pragma unroll
        for (int i = 0; i < 4; i++) {
            af[i]  = *(const bf16x8*)&As[cur][(wr + i * 16 + a) * 32 + g * 8];
            bfr[i] = *(const bf16x8*)&Bs[cur][(wc + i * 16 + a) * 32 + g * 8];
        }
#pragma unroll
        for (int i = 0; i < 4; i++)
#pragma unroll
            for (int j = 0; j < 4; j++) acc[i][j] = mfma_bf16(af[i], bfr[j], acc[i][j]);

        __syncthreads();   // readers done with buf cur; prefetched buf complete
        cur ^= 1;
    }
#undef GSTAGE

#pragma unroll
    for (int j = 0; j < 4; j++) {
        const int col = n0 + wc + j * 16 + a;
        const float bv = bias[col];
        if (MODE == 0) {
            float* Cf = (float*)C;
#pragma unroll
            for (int i = 0; i < 4; i++)
#pragma unroll
                for (int jr = 0; jr < 4; jr++) {
                    const int row = m0 + wr + i * 16 + g * 4 + jr;
                    Cf[(size_t)row * N + col] = acc[i][j][jr] + bv;
                }
        } else if (n0 < 2048) {  // Q/K part -> bf16, ldc = 2048
            unsigned short* Cb = (unsigned short*)C;
#pragma unroll
            for (int i = 0; i < 4; i++)
#pragma unroll
                for (int jr = 0; jr < 4; jr++) {
                    const int row = m0 + wr + i * 16 + g * 4 + jr;
                    Cb[(size_t)row * 2048 + col] = f2bf(acc[i][j][jr] + bv);
                }
        } else {  // V part -> vT[(b*16+h)][d][token], 4-token packs
            const int vd = col - 2048;
            const int hh = vd >> 6, dd = vd & 63;
#pragma unroll
            for (int i = 0; i < 4; i++) {
                const int token0 = m0 + wr + i * 16 + g * 4;
                const int bb = token0 >> 11, kl = token0 & 2047;
                ushort4v st;
#pragma unroll
                for (int jr = 0; jr < 4; jr++) st[jr] = f2bf(acc[i][j][jr] + bv);
                *(ushort4v*)(vT + ((size_t)((bb << 4) + hh) * 64 + dd) * 2048 + kl) = st;
            }
        }
    }
}

// ===========================================================================
// Causal flash attention v8b: KVBLK=128 (R13 structure, validated) +
// T5 s_setprio around the MFMA clusters (2 independent blocks/CU give the
// scheduler role diversity; m191 attn +4-7%).
// ===========================================================================

#define STAGE(bf_, t_)                                                  \
    {                                                                   \
        const size_t ko_ = (size_t)(t_) * 128 * LDQ;                    \
        const size_t vo_ = (size_t)(t_) * 128;                          \
        char* db_ = (char*)&KV[bf_][0] + w * 1024;                      \
        GLD16(sK0 + ko_, db_);                                          \
        GLD16(sK1 + ko_, db_ + 8192);                                   \
        GLD16(sV0 + vo_, db_ + 16384);                                  \
        GLD16(sV1 + vo_, db_ + 24576);                                  \
    }

__global__ void __launch_bounds__(512, 4) attn_fwd(const unsigned short* __restrict__ qk,
                                                   const unsigned short* __restrict__ vT,
                                                   unsigned short* __restrict__ o) {
    constexpr int SL = 2048, DH = 64, LDQ = 2048;
    constexpr float GAMMA = 0.18033688011112042f;  // 0.125 * log2(e)
    const int bh = blockIdx.x & 31;                // bh&7 -> XCD pinning
    const int s = blockIdx.x >> 5;                 // 0..15
    const int qb = (s < 8) ? 15 - s : s - 8;       // q-block; RR pairs sum 17 tiles
    const int b = bh >> 4, h = bh & 15;
    const int tid = threadIdx.x;
    const int w = tid >> 6, lane = tid & 63;       // w: 0..7
    const int n = lane & 15, g = lane >> 4;

    // per buffer: K[128][64] shorts 0..8191 | V[64][128] shorts 8192..16383
    __shared__ __attribute__((aligned(16))) unsigned short KV[2][16384];

    const int qs = qb * 128 + w * 16 + n;          // this lane's q row
    const int nt = qb + 1;                         // 128-wide k-tiles

    // ---- Q fragments (B-operand), prescaled into log2 domain ----
    bf16x8 qf[2];
    {
        const unsigned short* qp = qk + (size_t)(b * SL + qs) * LDQ + h * DH + g * 8;
        short8 la = *(const short8*)qp, lb = *(const short8*)(qp + 32);
        short8 s0, s1;
#pragma unroll
        for (int e = 0; e < 8; e++) {
            s0[e] = (short)f2bf(bf2f((unsigned short)la[e]) * GAMMA);
            s1[e] = (short)f2bf(bf2f((unsigned short)lb[e]) * GAMMA);
        }
        qf[0] = __builtin_bit_cast(bf16x8, s0);
        qf[1] = __builtin_bit_cast(bf16x8, s1);
    }

    // ---- staging sources (per-lane, pre-swizzled) ----
    const int rK = tid >> 3;
    const int xrK = (rK & 3) | (((rK >> 3) & 1) << 2);   // same for rK and rK+64
    const int csK = (((tid & 7) ^ xrK) << 3);
    const unsigned short* sK0 = qk + (size_t)(b * SL + rK) * LDQ + 1024 + h * DH + csK;
    const unsigned short* sK1 = sK0 + (size_t)64 * LDQ;
    const int dV = tid >> 4;
    const int csV = (((tid & 15) ^ (dV & 7)) << 3);
    const unsigned short* sV0 = vT + (size_t)bh * DH * SL + (size_t)dV * SL + csV;
    const unsigned short* sV1 = sV0 + (size_t)32 * SL;

    // ---- fragment read offsets (swizzled) ----
    const int srow = 8 * (n >> 2) + (n & 3);
    const int xrq = (n & 3) | (((n >> 2) & 1) << 2);  // xr of all QKT rows
    const int offK0 = ((g ^ xrq) << 3);               // d 0..31 chunk
    const int offK1 = offK0 ^ 32;                     // d 32..63 chunk
    int offV[4];
#pragma unroll
    for (int kc = 0; kc < 4; kc++) offV[kc] = (((4 * kc + g) ^ (n & 7)) << 3);

    f32x4 of[4];
#pragma unroll
    for (int i = 0; i < 4; i++) of[i] = (f32x4)(0.0f);
    float m_i = -1e30f, l_i = 0.0f;

    STAGE(0, 0);
    __syncthreads();  // drains vmcnt before barrier

    for (int t = 0; t < nt; ++t) {
        const unsigned short* kvb = &KV[t & 1][0];
        if (t + 1 < nt) STAGE((t & 1) ^ 1, t + 1);  // loads fly during compute

        // ---- S^T: 8 fragments cover 128 k-rows ----
        f32x4 p[8];
        __builtin_amdgcn_s_setprio(1);
#pragma unroll
        for (int f = 0; f < 8; f++) {
            const int r_ = srow + ((f >> 1) << 5) + ((f & 1) << 2);
            const bf16x8 ka_ = *(const bf16x8*)&kvb[r_ * 64 + offK0];
            const bf16x8 kc_ = *(const bf16x8*)&kvb[r_ * 64 + offK1];
            f32x4 acc_ = (f32x4)(0.0f);
            acc_ = mfma_bf16(ka_, qf[0], acc_);
            acc_ = mfma_bf16(kc_, qf[1], acc_);
            p[f] = acc_;
        }
        __builtin_amdgcn_s_setprio(0);

        // ---- causal mask (diagonal tile only) ----
        if (t == nt - 1) {
            const int k0 = t * 128;
#pragma unroll
            for (int f = 0; f < 8; f++) {
                const int kb_ = k0 + ((f >> 1) << 5) + ((f & 1) << 2) + 8 * g;
#pragma unroll
                for (int e = 0; e < 4; e++)
                    if (kb_ + e > qs) p[f][e] = -1e30f;
            }
        }

        // ---- in-register softmax (log2 domain), defer-max ----
        float mx = -1e30f;
#pragma unroll
        for (int f = 0; f < 8; f++) {
            const float a_ = fmaxf(fmaxf(p[f][0], p[f][1]), fmaxf(p[f][2], p[f][3]));
            mx = fmaxf(mx, a_);
        }
        mx = fmaxf(mx, __shfl_xor(mx, 16));
        mx = fmaxf(mx, __shfl_xor(mx, 32));
        if (!__all(mx <= m_i + 8.0f)) {
            const float mn_ = fmaxf(m_i, mx);
            const float al_ = __builtin_amdgcn_exp2f(m_i - mn_);
            l_i *= al_;
#pragma unroll
            for (int d_ = 0; d_ < 4; d_++) of[d_] = of[d_] * al_;
            m_i = mn_;
        }
        float rs = 0.0f;
#pragma unroll
        for (int f = 0; f < 8; f++)
#pragma unroll
            for (int e = 0; e < 4; e++) {
                p[f][e] = __builtin_amdgcn_exp2f(p[f][e] - m_i);
                rs += p[f][e];
            }
        l_i += rs;

        // ---- pack to PV B-fragments (sigma: pure in-lane) ----
        bf16x8 pf[4];
#pragma unroll
        for (int kc = 0; kc < 4; kc++) {
            uint4v u_;
            u_[0] = pkbf(p[2 * kc][0], p[2 * kc][1]);
            u_[1] = pkbf(p[2 * kc][2], p[2 * kc][3]);
            u_[2] = pkbf(p[2 * kc + 1][0], p[2 * kc + 1][1]);
            u_[3] = pkbf(p[2 * kc + 1][2], p[2 * kc + 1][3]);
            pf[kc] = __builtin_bit_cast(bf16x8, u_);
        }

        // ---- O^T += V^T P^T ----
        const unsigned short* vb = kvb + 8192;
        __builtin_amdgcn_s_setprio(1);
#pragma unroll
        for (int df = 0; df < 4; df++) {
            const int vrow = (df * 16 + n) * 128;
#pragma unroll
            for (int kc = 0; kc < 4; kc++) {
                const bf16x8 va_ = *(const bf16x8*)&vb[vrow + offV[kc]];
                of[df] = mfma_bf16(va_, pf[kc], of[df]);
            }
        }
        __builtin_amdgcn_s_setprio(0);

        __syncthreads();  // readers done with buf t&1; staged buf complete
    }

    // ---- epilogue: lane holds O[d = df*16+4g+r][q = qs] ----
    float rl = l_i;
    rl += __shfl_xor(rl, 16);
    rl += __shfl_xor(rl, 32);
    const float inv = 1.0f / rl;
    unsigned short* op = o + (size_t)(b * SL + qs) * 1024 + h * DH + 4 * g;
#pragma unroll
    for (int df = 0; df < 4; df++) {
        ushort4v st;
#pragma unroll
        for (int r = 0; r < 4; r++) st[r] = f2bf(of[df][r] * inv);
        *(ushort4v*)(op + df * 16) = st;
    }
}

// ---------------------------------------------------------------------------
extern "C" void kernel_launch(void* const* d_in, const int* in_sizes, int n_in,
                              void* d_out, int out_size, void* d_ws, size_t ws_size,
                              hipStream_t stream) {
    (void)in_sizes; (void)n_in; (void)out_size; (void)ws_size;
    const float* x    = (const float*)d_in[0];
    const float* Wqkv = (const float*)d_in[1];
    const float* bqkv = (const float*)d_in[2];
    const float* Wout = (const float*)d_in[3];
    const float* bout = (const float*)d_in[4];
    float* out = (float*)d_out;

    const int BS = 2, SL = 2048, DM = 1024;
    const int M = BS * SL;   // 4096
    const int N1 = 3 * DM;   // 3072
    const int K = DM;        // 1024

    // ws layout: x_bf 8M | wqkv_bf 6M | wout_bf 2M | qk 16M | vT 8M | attn_o 8M = 48M
    char* ws = (char*)d_ws;
    unsigned short* x_bf    = (unsigned short*)(ws);
    unsigned short* wqkv_bf = (unsigned short*)(ws + (8u << 20));
    unsigned short* wout_bf = (unsigned short*)(ws + (14u << 20));
    unsigned short* qkbuf   = (unsigned short*)(ws + (16u << 20));
    unsigned short* vTbuf   = (unsigned short*)(ws + (32u << 20));
    unsigned short* attn_o  = (unsigned short*)(ws + (40u << 20));

    cvt_all<<<2048, 256, 0, stream>>>(x, Wqkv, Wout, x_bf, wqkv_bf, wout_bf);

    gemm_bt<1><<<dim3(N1 / 128 * (M / 128)), 256, 0, stream>>>(x_bf, wqkv_bf, bqkv, qkbuf, vTbuf, M, N1, K);

    attn_fwd<<<dim3(512), 512, 0, stream>>>(qkbuf, vTbuf, attn_o);

    gemm_bt<0><<<dim3(DM / 128 * (M / 128)), 256, 0, stream>>>(attn_o, wout_bf, bout, out, nullptr, M, DM, K);
}